// Round 1
// baseline (555.517 us; speedup 1.0000x reference)
//
#include <hip/hip_runtime.h>
#include <hip/hip_bf16.h>

#define WD 50
#define PD 5
#define HID 230
#define RELN 53
#define LLEN 120
#define BAGS 512
#define BB 8
#define NSENT 4096
#define QL 8
#define CIN 160     // 3*WD + 2*PD
#define KTOT 480    // 3 * CIN
#define XROW 168    // padded LDS row (bf16 elems), 16B-aligned stride
#define XROWS 130   // rows -1..128 (l + tap), rows outside [1,120] zero

typedef __attribute__((ext_vector_type(4))) float f32x4;
typedef __attribute__((ext_vector_type(8))) short short8;

__device__ __forceinline__ float bf2f(short u) {
    union { float f; unsigned int i; } v;
    v.i = ((unsigned int)(unsigned short)u) << 16;
    return v.f;
}
__device__ __forceinline__ short f2bf(float f) {
    union { float f; unsigned int i; } v; v.f = f;
    unsigned int r = v.i + 0x7FFFu + ((v.i >> 16) & 1u);  // RNE
    return (short)(r >> 16);
}

// ---------------- build per-bag query q[BAGS][QL][WD] ----------------
__global__ void build_q_kernel(const int* __restrict__ Q, const int* __restrict__ E1,
                               const int* __restrict__ E2, const float* __restrict__ W_word,
                               float* __restrict__ q_ws) {
    int b = blockIdx.x;
    int d = threadIdx.x;
    if (d >= WD) return;
    float e1 = 0.5f * (W_word[E1[2 * b] * WD + d] + W_word[E1[2 * b + 1] * WD + d]);
    float e2 = 0.5f * (W_word[E2[2 * b] * WD + d] + W_word[E2[2 * b + 1] * WD + d]);
    for (int j = 0; j < QL; ++j) {
        float v;
        if (j == QL - 4)      v = e1;
        else if (j == QL - 2) v = e2;
        else                  v = W_word[Q[b * QL + j] * WD + d];
        q_ws[(b * QL + j) * WD + d] = v;
    }
}

// ---------------- pack conv weights -> Wt[256][480] bf16 (row = h) ----------------
__global__ void pack_w_kernel(const float* __restrict__ conv_W, short* __restrict__ wt) {
    int i = blockIdx.x * 256 + threadIdx.x;
    if (i >= 256 * KTOT) return;
    int h = i / KTOT, kc = i % KTOT;
    float v = (h < HID) ? conv_W[kc * HID + h] : 0.f;   // conv_W[(k*160+c)*230 + h]
    wt[i] = f2bf(v);
}

// ---------------- fused per-sentence: attention -> x -> conv(k=3) -> max -> relu ----------------
__launch_bounds__(512)
__global__ void sent_kernel(const int* __restrict__ X, const int* __restrict__ XP1,
                            const int* __restrict__ XP2,
                            const float* __restrict__ W_word,
                            const float* __restrict__ W_pos1, const float* __restrict__ W_pos2,
                            const float* __restrict__ w_s, const float* __restrict__ b_s,
                            const float* __restrict__ w_q, const float* __restrict__ b_q,
                            const float* __restrict__ w_sq, const float* __restrict__ b_sq,
                            const float* __restrict__ conv_b,
                            const float* __restrict__ q_ws, const short* __restrict__ wt,
                            float* __restrict__ enc) {
    extern __shared__ char smem[];
    short* xl  = (short*)smem;                       // [130][168] bf16
    float* sS  = (float*)(smem + XROWS * XROW * 2);  // [120][52]
    float* qv  = sS + 120 * 52;                      // [8][52]
    float* qw  = qv + QL * 52;                       // [8][52] q*w_sq
    float* hm  = qw + QL * 52;                       // [120][8] h then a
    float* ssv = hm + 120 * 8;                       // [120]
    float* hmx = ssv + 120;                          // [120]
    float* bat = hmx + 120;                          // [120]
    float* qsv = bat + 120;                          // [8]
    float* q2s = qsv + 8;                            // [52]
    float* smax = q2s + 52;                          // [2][256]
    float* red  = smax + 512;                        // [2]
    int* xid = (int*)(red + 2);                      // [120]
    int* xp1 = xid + 120;                            // [120]
    int* xp2 = xp1 + 120;                            // [120]

    const int tid = threadIdx.x;
    const int n = blockIdx.x;
    const int bag = n >> 3;

    // stage indices
    for (int i = tid; i < LLEN; i += 512) {
        xid[i] = X[n * LLEN + i];
        xp1[i] = XP1[n * LLEN + i];
        xp2[i] = XP2[n * LLEN + i];
    }
    // load q, qw
    for (int i = tid; i < QL * WD; i += 512) {
        int j = i / WD, d = i % WD;
        float v = q_ws[(bag * QL + j) * WD + d];
        qv[j * 52 + d] = v;
        qw[j * 52 + d] = v * w_sq[d];
    }
    __syncthreads();
    // gather s
    for (int i = tid; i < LLEN * WD; i += 512) {
        int l = i / WD, d = i % WD;
        sS[l * 52 + d] = W_word[xid[l] * WD + d];
    }
    __syncthreads();
    // ss[l] = s.w_s + b_s + b_sq ; qs[j] = q.w_q + b_q
    float bsv = b_s[0] + b_sq[0];
    for (int l = tid; l < LLEN; l += 512) {
        float acc = bsv;
        for (int d = 0; d < WD; ++d) acc += sS[l * 52 + d] * w_s[d];
        ssv[l] = acc;
    }
    if (tid < QL) {
        float acc = b_q[0];
        for (int d = 0; d < WD; ++d) acc += qv[tid * 52 + d] * w_q[d];
        qsv[tid] = acc;
    }
    __syncthreads();
    // h[l][j]
    for (int i = tid; i < LLEN * QL; i += 512) {
        int l = i >> 3, j = i & 7;
        float acc = 0.f;
        for (int d = 0; d < WD; ++d) acc += sS[l * 52 + d] * qw[j * 52 + d];
        hm[i] = acc + ssv[l] + qsv[j];
    }
    __syncthreads();
    // softmax over j (in-place -> a), keep row max in hmx
    for (int l = tid; l < LLEN; l += 512) {
        float m = hm[l * 8];
        for (int j = 1; j < 8; ++j) m = fmaxf(m, hm[l * 8 + j]);
        hmx[l] = m;
        float e[8], sum = 0.f;
        for (int j = 0; j < 8; ++j) { e[j] = expf(hm[l * 8 + j] - m); sum += e[j]; }
        float inv = 1.f / sum;
        for (int j = 0; j < 8; ++j) hm[l * 8 + j] = e[j] * inv;
    }
    __syncthreads();
    // b_att = softmax over l of hmx
    if (tid < 64) {
        float v = (tid < LLEN) ? hmx[tid] : -1e30f;
        float v2 = (tid + 64 < LLEN) ? hmx[tid + 64] : -1e30f;
        v = fmaxf(v, v2);
        for (int o = 32; o >= 1; o >>= 1) v = fmaxf(v, __shfl_xor(v, o, 64));
        if (tid == 0) red[0] = v;
    }
    __syncthreads();
    float rmax = red[0];
    for (int l = tid; l < LLEN; l += 512) bat[l] = expf(hmx[l] - rmax);
    __syncthreads();
    if (tid < 64) {
        float v = (tid < LLEN ? bat[tid] : 0.f) + (tid + 64 < LLEN ? bat[tid + 64] : 0.f);
        for (int o = 32; o >= 1; o >>= 1) v += __shfl_xor(v, o, 64);
        if (tid == 0) red[1] = v;
    }
    __syncthreads();
    // q2s[d] = sum_l b_att[l]*s[l][d] / sum
    if (tid < WD) {
        float acc = 0.f;
        for (int l = 0; l < LLEN; ++l) acc += bat[l] * sS[l * 52 + tid];
        q2s[tid] = acc / red[1];
    }
    __syncthreads();
    // build x tile (zero padded)
    for (int i = tid; i < XROWS * XROW; i += 512) xl[i] = 0;
    __syncthreads();
    for (int i = tid; i < LLEN * CIN; i += 512) {
        int l = i / CIN, c = i % CIN;
        float v;
        if (c < 50) {
            v = sS[l * 52 + c];
        } else if (c < 100) {
            int d = c - 50;
            float s2q = 0.f;
            for (int j = 0; j < 8; ++j) s2q += hm[l * 8 + j] * qv[j * 52 + d];
            v = sS[l * 52 + d] * s2q;
        } else if (c < 150) {
            int d = c - 100;
            v = sS[l * 52 + d] * q2s[d];
        } else if (c < 155) {
            v = W_pos1[xp1[l] * PD + (c - 150)];
        } else {
            v = W_pos2[xp2[l] * PD + (c - 155)];
        }
        xl[(l + 1) * XROW + c] = f2bf(v);
    }
    __syncthreads();

    // ---- MFMA conv: M=128 (l), N=256 (h), K=480 ----
    const int lane = tid & 63;
    const int wid = tid >> 6;
    const int wm = wid >> 2;   // 0..1  -> rows 64*wm..
    const int wn = wid & 3;    // 0..3  -> cols 64*wn..
    const int r16 = lane & 15;
    const int g = lane >> 4;

    f32x4 acc[4][4];
    for (int a = 0; a < 4; ++a)
        for (int b2 = 0; b2 < 4; ++b2) acc[a][b2] = (f32x4){0.f, 0.f, 0.f, 0.f};

    const short* wbase = wt + (64 * wn + r16) * KTOT + g * 8;
    const int arow0 = 64 * wm + r16;

    for (int ks = 0; ks < 15; ++ks) {
        const int tap = ks / 5;                    // K-steps align with taps (160 = 5*32)
        const int c0 = (ks % 5) * 32 + g * 8;
        short8 bfr[4];
        for (int nf = 0; nf < 4; ++nf)
            bfr[nf] = *(const short8*)(wbase + nf * 16 * KTOT + 32 * ks);
        short8 afr[4];
        for (int mf = 0; mf < 4; ++mf)
            afr[mf] = *(const short8*)(xl + (arow0 + 16 * mf + tap) * XROW + c0);
        for (int mf = 0; mf < 4; ++mf)
            for (int nf = 0; nf < 4; ++nf)
                acc[mf][nf] = __builtin_amdgcn_mfma_f32_16x16x32_bf16(
                    afr[mf], bfr[nf], acc[mf][nf], 0, 0, 0);
    }

    // epilogue: max over l (mask l>=120), reduce, write enc
    for (int nf = 0; nf < 4; ++nf) {
        float m = -1e30f;
        for (int mf = 0; mf < 4; ++mf) {
            int lbase = 64 * wm + 16 * mf + 4 * g;
            for (int r = 0; r < 4; ++r)
                if (lbase + r < LLEN) m = fmaxf(m, acc[mf][nf][r]);
        }
        m = fmaxf(m, __shfl_xor(m, 16, 64));
        m = fmaxf(m, __shfl_xor(m, 32, 64));
        if (lane < 16) smax[wm * 256 + 64 * wn + 16 * nf + lane] = m;
    }
    __syncthreads();
    for (int h = tid; h < HID; h += 512) {
        float v = fmaxf(smax[h], smax[256 + h]) + conv_b[h];
        enc[n * HID + h] = fmaxf(v, 0.f);
    }
}

// ---------------- bag self-attention + relation scores ----------------
__global__ void bag_kernel(const float* __restrict__ enc, const int* __restrict__ X_Rel,
                           const float* __restrict__ rel_W, const float* __restrict__ rel_b,
                           float* __restrict__ out) {
    __shared__ float bagv[BB][232];
    __shared__ float bag2[BB][232];
    __shared__ float att[BB][BB];
    __shared__ float relv[232];
    __shared__ float repv[232];
    __shared__ float sc[BB], sc2[BB];
    const int b = blockIdx.x, t = threadIdx.x;

    for (int i = t; i < BB * HID; i += 256) {
        int r = i / HID, d = i % HID;
        bagv[r][d] = enc[(b * BB + r) * HID + d];
    }
    __syncthreads();
    if (t < 64) {
        int i = t >> 3, j = t & 7;
        float acc = 0.f;
        for (int d = 0; d < HID; ++d) acc += bagv[i][d] * bagv[j][d];
        att[i][j] = acc * (1.0f / sqrtf(230.0f));
    }
    __syncthreads();
    if (t < 8) {
        float m = att[t][0];
        for (int j = 1; j < 8; ++j) m = fmaxf(m, att[t][j]);
        float e[8], s = 0.f;
        for (int j = 0; j < 8; ++j) { e[j] = expf(att[t][j] - m); s += e[j]; }
        float inv = 1.f / s;
        for (int j = 0; j < 8; ++j) att[t][j] = e[j] * inv;
    }
    __syncthreads();
    for (int i = t; i < BB * HID; i += 256) {
        int r = i / HID, d = i % HID;
        float acc = 0.f;
        for (int j = 0; j < 8; ++j) acc += att[r][j] * bagv[j][d];
        bag2[r][d] = acc;
    }
    if (t < HID) relv[t] = rel_W[X_Rel[b] * HID + t];
    __syncthreads();
    if (t < 8) {
        float acc = 0.f;
        for (int d = 0; d < HID; ++d) acc += bag2[t][d] * relv[d];
        sc[t] = acc;
    }
    __syncthreads();
    if (t < 8) {
        float m = sc[0];
        for (int j = 1; j < 8; ++j) m = fmaxf(m, sc[j]);
        sc2[t] = expf(sc[t] - m);
    }
    __syncthreads();
    if (t < HID) {
        float sum = 0.f;
        for (int j = 0; j < 8; ++j) sum += sc2[j];
        float acc = 0.f;
        for (int j = 0; j < 8; ++j) acc += sc2[j] * bag2[j][t];
        repv[t] = acc / sum;
    }
    __syncthreads();
    if (t < RELN) {
        float acc = rel_b[t];
        for (int d = 0; d < HID; ++d) acc += repv[d] * rel_W[t * HID + d];
        out[b * RELN + t] = acc;
    }
}

extern "C" void kernel_launch(void* const* d_in, const int* in_sizes, int n_in,
                              void* d_out, int out_size, void* d_ws, size_t ws_size,
                              hipStream_t stream) {
    const int* X       = (const int*)d_in[0];
    const int* XP1     = (const int*)d_in[1];
    const int* XP2     = (const int*)d_in[2];
    const int* E1      = (const int*)d_in[3];
    const int* E2      = (const int*)d_in[4];
    const int* Q       = (const int*)d_in[10];
    const int* X_Rel   = (const int*)d_in[11];
    const float* W_word = (const float*)d_in[12];
    const float* W_pos1 = (const float*)d_in[13];
    const float* W_pos2 = (const float*)d_in[14];
    const float* w_s   = (const float*)d_in[15];
    const float* b_s   = (const float*)d_in[16];
    const float* w_q   = (const float*)d_in[17];
    const float* b_q   = (const float*)d_in[18];
    const float* w_sq  = (const float*)d_in[19];
    const float* b_sq  = (const float*)d_in[20];
    const float* conv_W = (const float*)d_in[21];
    const float* conv_b = (const float*)d_in[22];
    const float* rel_W = (const float*)d_in[23];
    const float* rel_b = (const float*)d_in[24];
    float* out = (float*)d_out;

    char* ws = (char*)d_ws;
    float* q_ws = (float*)ws;                      // 512*8*50 f32
    float* enc  = q_ws + BAGS * QL * WD;           // 4096*230 f32
    short* wt   = (short*)(enc + NSENT * HID);     // 256*480 bf16

    build_q_kernel<<<BAGS, 64, 0, stream>>>(Q, E1, E2, W_word, q_ws);
    pack_w_kernel<<<(256 * KTOT) / 256, 256, 0, stream>>>(conv_W, wt);

    const size_t lds_bytes = (size_t)XROWS * XROW * 2  // x tile
        + 4 * (120 * 52 + 2 * QL * 52 + 120 * 8 + 120 * 3 + 8 + 52 + 512 + 2)
        + 4 * 360;
    sent_kernel<<<NSENT, 512, lds_bytes, stream>>>(
        X, XP1, XP2, W_word, W_pos1, W_pos2,
        w_s, b_s, w_q, b_q, w_sq, b_sq, conv_b, q_ws, wt, enc);

    bag_kernel<<<BAGS, 256, 0, stream>>>(enc, X_Rel, rel_W, rel_b, out);
}

// Round 2
// 253.217 us; speedup vs baseline: 2.1938x; 2.1938x over previous
//
#include <hip/hip_runtime.h>
#include <hip/hip_bf16.h>

#define WD 50
#define PD 5
#define HID 230
#define RELN 53
#define LLEN 120
#define BAGS 512
#define BB 8
#define NSENT 4096
#define QL 8
#define CIN 160     // 3*WD + 2*PD
#define KTOT 480    // 3 * CIN
#define XROW 168    // padded LDS row (bf16 elems); 336B stride = 2-way bank alias (free)
#define XROWS 130   // rows -1..128 (l + tap); rows outside [1,120] stay zero

typedef __attribute__((ext_vector_type(4))) float f32x4;
typedef __attribute__((ext_vector_type(8))) short short8;

__device__ __forceinline__ float bf2f(short u) {
    union { float f; unsigned int i; } v;
    v.i = ((unsigned int)(unsigned short)u) << 16;
    return v.f;
}
__device__ __forceinline__ short f2bf(float f) {
    union { float f; unsigned int i; } v; v.f = f;
    unsigned int r = v.i + 0x7FFFu + ((v.i >> 16) & 1u);  // RNE
    return (short)(r >> 16);
}

// ---------------- build per-bag query q[BAGS][QL][WD] ----------------
__global__ void build_q_kernel(const int* __restrict__ Q, const int* __restrict__ E1,
                               const int* __restrict__ E2, const float* __restrict__ W_word,
                               float* __restrict__ q_ws) {
    int b = blockIdx.x;
    int d = threadIdx.x;
    if (d >= WD) return;
    float e1 = 0.5f * (W_word[E1[2 * b] * WD + d] + W_word[E1[2 * b + 1] * WD + d]);
    float e2 = 0.5f * (W_word[E2[2 * b] * WD + d] + W_word[E2[2 * b + 1] * WD + d]);
    for (int j = 0; j < QL; ++j) {
        float v;
        if (j == QL - 4)      v = e1;
        else if (j == QL - 2) v = e2;
        else                  v = W_word[Q[b * QL + j] * WD + d];
        q_ws[(b * QL + j) * WD + d] = v;
    }
}

// ---------------- pack conv weights -> Wt[256][480] bf16 (row = h) ----------------
__global__ void pack_w_kernel(const float* __restrict__ conv_W, short* __restrict__ wt) {
    int i = blockIdx.x * 256 + threadIdx.x;
    if (i >= 256 * KTOT) return;
    int h = i / KTOT, kc = i % KTOT;
    float v = (h < HID) ? conv_W[kc * HID + h] : 0.f;   // conv_W[(k*160+c)*230 + h]
    wt[i] = f2bf(v);
}

// ---------------- fused per-sentence: attention (MFMA) -> x -> conv(k=3) -> max -> relu ----------------
__launch_bounds__(512, 4)
__global__ void sent_kernel(const int* __restrict__ X, const int* __restrict__ XP1,
                            const int* __restrict__ XP2,
                            const float* __restrict__ W_word,
                            const float* __restrict__ W_pos1, const float* __restrict__ W_pos2,
                            const float* __restrict__ w_s, const float* __restrict__ b_s,
                            const float* __restrict__ w_q, const float* __restrict__ b_q,
                            const float* __restrict__ w_sq, const float* __restrict__ b_sq,
                            const float* __restrict__ conv_b,
                            const float* __restrict__ q_ws, const short* __restrict__ wt,
                            float* __restrict__ enc) {
    extern __shared__ char smem[];
    short* xl  = (short*)smem;                          // [130][168] bf16 (x tile; cols 0..49 = s)
    short* abf = xl + XROWS * XROW;                     // [128][32] bf16 a (K-padded)
    short* qtb = abf + 128 * 32;                        // [64][32] bf16 q^T (rows d, cols j)
    short* qwb = qtb + 64 * 32;                         // [16][64] bf16 q*w_sq (rows j, cols d)
    float* hm  = (float*)(qwb + 16 * 64);               // [120][8] raw h' (excl ssv)
    float* hmx = hm + LLEN * 8;                         // [120]
    float* bat = hmx + LLEN;                            // [120]
    float* qsv = bat + LLEN;                            // [8]
    float* q2s = qsv + QL;                              // [52]
    float* smax = q2s + 52;                             // [2][256] (also q2s partial scratch)
    float* red  = smax + 512;                           // [2]
    int* xid = (int*)(red + 2);                         // [120]
    int* xp1 = xid + LLEN;                              // [120]
    int* xp2 = xp1 + LLEN;                              // [120]

    const int tid = threadIdx.x;
    const int n = blockIdx.x;
    const int bag = n >> 3;
    const int lane = tid & 63;
    const int wid = tid >> 6;
    const int r16 = lane & 15;
    const int g = lane >> 4;

    // ---- P0: zero bf16 region (xl+abf+qtb+qwb = 58016B), stage indices ----
    {
        int* z = (int*)smem;
        for (int i = tid; i < 14504; i += 512) z[i] = 0;
        for (int i = tid; i < LLEN; i += 512) {
            xid[i] = X[n * LLEN + i];
            xp1[i] = XP1[n * LLEN + i];
            xp2[i] = XP2[n * LLEN + i];
        }
    }
    __syncthreads();

    // ---- P1: gather s -> xl cols 0..49; pos -> cols 150..159; build qwb/qtb; qsv ----
    for (int i = tid; i < LLEN * WD; i += 512) {
        int l = i / WD, d = i % WD;
        xl[(l + 1) * XROW + d] = f2bf(W_word[xid[l] * WD + d]);
    }
    if (tid < QL * WD) {
        int j = tid / WD, d = tid % WD;
        float v = q_ws[(bag * QL + j) * WD + d];
        qwb[j * 64 + d] = f2bf(v * w_sq[d]);
        qtb[d * 32 + j] = f2bf(v);
    }
    for (int i = tid; i < LLEN * 2 * PD; i += 512) {
        int l = i / 10, c = i % 10;
        float v = (c < PD) ? W_pos1[xp1[l] * PD + c] : W_pos2[xp2[l] * PD + (c - PD)];
        xl[(l + 1) * XROW + 150 + c] = f2bf(v);
    }
    if (tid < QL) {
        float acc = b_q[0];
        for (int d = 0; d < WD; ++d) acc += q_ws[(bag * QL + tid) * WD + d] * w_q[d];
        qsv[tid] = acc;
    }
    __syncthreads();

    // ---- P2: h' = s @ qw^T via MFMA (M=128 l, N=16 j, K=64) ----
    {
        const float bsq = b_sq[0];
        f32x4 hacc = (f32x4){0.f, 0.f, 0.f, 0.f};
        for (int ks2 = 0; ks2 < 2; ++ks2) {
            short8 af = *(const short8*)(xl + (1 + 16 * wid + r16) * XROW + ks2 * 32 + g * 8);
            short8 bf = *(const short8*)(qwb + r16 * 64 + ks2 * 32 + g * 8);
            hacc = __builtin_amdgcn_mfma_f32_16x16x32_bf16(af, bf, hacc, 0, 0, 0);
        }
        if (r16 < QL) {
            float qs = qsv[r16] + bsq;
            for (int r = 0; r < 4; ++r) {
                int l = 16 * wid + 4 * g + r;
                if (l < LLEN) hm[l * 8 + r16] = hacc[r] + qs;
            }
        }
    }
    __syncthreads();

    // ---- P3: per-row ssv dot + softmax over j; a -> abf bf16; hmx[l] = rowmax + ssv ----
    if (tid < LLEN) {
        const int l = tid;
        const short* srow = xl + (l + 1) * XROW;
        float sv = b_s[0];
        for (int c = 0; c < 48; c += 8) {
            short8 v = *(const short8*)(srow + c);
            for (int j = 0; j < 8; ++j) sv += bf2f(v[j]) * w_s[c + j];
        }
        sv += bf2f(srow[48]) * w_s[48] + bf2f(srow[49]) * w_s[49];
        float a[8], m = -1e30f;
        for (int j = 0; j < 8; ++j) { a[j] = hm[l * 8 + j]; m = fmaxf(m, a[j]); }
        hmx[l] = m + sv;
        float sum = 0.f;
        for (int j = 0; j < 8; ++j) { a[j] = expf(a[j] - m); sum += a[j]; }
        float inv = 1.f / sum;
        for (int j = 0; j < 8; ++j) abf[l * 32 + j] = f2bf(a[j] * inv);
    }
    __syncthreads();

    // ---- P4: b_att softmax over l, then q2s ----
    if (tid < 64) {
        float v = (tid < LLEN) ? hmx[tid] : -1e30f;
        float v2 = (tid + 64 < LLEN) ? hmx[tid + 64] : -1e30f;
        v = fmaxf(v, v2);
        for (int o = 32; o >= 1; o >>= 1) v = fmaxf(v, __shfl_xor(v, o, 64));
        if (tid == 0) red[0] = v;
    }
    __syncthreads();
    if (tid < LLEN) bat[tid] = expf(hmx[tid] - red[0]);
    __syncthreads();
    if (tid < 64) {
        float v = (tid < LLEN ? bat[tid] : 0.f) + (tid + 64 < LLEN ? bat[tid + 64] : 0.f);
        for (int o = 32; o >= 1; o >>= 1) v += __shfl_xor(v, o, 64);
        if (tid == 0) red[1] = v;
    } else if (tid >= 64 && tid < 64 + 8 * WD) {
        int c = (tid - 64) / WD, d = (tid - 64) % WD;
        float acc = 0.f;
        for (int l = c * 15; l < c * 15 + 15; ++l)
            acc += bat[l] * bf2f(xl[(l + 1) * XROW + d]);
        smax[c * 52 + d] = acc;
    }
    __syncthreads();
    if (tid < WD) {
        float acc = 0.f;
        for (int c = 0; c < 8; ++c) acc += smax[c * 52 + tid];
        q2s[tid] = acc / red[1];
    }
    __syncthreads();

    // ---- P5: s2q = a @ q via MFMA; epilogue writes x cols 50..99.  P6: cols 100..149 ----
    {
        short8 af = *(const short8*)(abf + (16 * wid + r16) * 32 + g * 8);
        for (int nt = 0; nt < 4; ++nt) {
            short8 bf = *(const short8*)(qtb + (16 * nt + r16) * 32 + g * 8);
            f32x4 acc2 = (f32x4){0.f, 0.f, 0.f, 0.f};
            acc2 = __builtin_amdgcn_mfma_f32_16x16x32_bf16(af, bf, acc2, 0, 0, 0);
            int d = 16 * nt + r16;
            if (d < WD) {
                for (int r = 0; r < 4; ++r) {
                    int l = 16 * wid + 4 * g + r;
                    if (l < LLEN) {
                        float s = bf2f(xl[(l + 1) * XROW + d]);
                        xl[(l + 1) * XROW + 50 + d] = f2bf(s * acc2[r]);
                    }
                }
            }
        }
    }
    for (int i = tid; i < LLEN * WD; i += 512) {
        int l = i / WD, d = i % WD;
        float s = bf2f(xl[(l + 1) * XROW + d]);
        xl[(l + 1) * XROW + 100 + d] = f2bf(s * q2s[d]);
    }
    __syncthreads();

    // ---- P7: conv MFMA: M=128 (l), N=256 (h), K=480 ----
    const int wm = wid >> 2;   // 0..1
    const int wn = wid & 3;    // 0..3
    f32x4 acc[4][4];
    for (int a = 0; a < 4; ++a)
        for (int b2 = 0; b2 < 4; ++b2) acc[a][b2] = (f32x4){0.f, 0.f, 0.f, 0.f};

    const short* wbase = wt + (64 * wn + r16) * KTOT + g * 8;
    const int arow0 = 64 * wm + r16;

    for (int ks = 0; ks < 15; ++ks) {
        const int tap = ks / 5;                    // K-steps align with taps (160 = 5*32)
        const int c0 = (ks % 5) * 32 + g * 8;
        short8 afr[4];
        for (int mf = 0; mf < 4; ++mf)
            afr[mf] = *(const short8*)(xl + (arow0 + 16 * mf + tap) * XROW + c0);
        for (int nf = 0; nf < 4; ++nf) {
            short8 bfr = *(const short8*)(wbase + nf * 16 * KTOT + 32 * ks);
            for (int mf = 0; mf < 4; ++mf)
                acc[mf][nf] = __builtin_amdgcn_mfma_f32_16x16x32_bf16(
                    afr[mf], bfr, acc[mf][nf], 0, 0, 0);
        }
    }

    // epilogue: max over l (mask l>=120), reduce, write enc
    for (int nf = 0; nf < 4; ++nf) {
        float m = -1e30f;
        for (int mf = 0; mf < 4; ++mf) {
            int lbase = 64 * wm + 16 * mf + 4 * g;
            for (int r = 0; r < 4; ++r)
                if (lbase + r < LLEN) m = fmaxf(m, acc[mf][nf][r]);
        }
        m = fmaxf(m, __shfl_xor(m, 16, 64));
        m = fmaxf(m, __shfl_xor(m, 32, 64));
        if (lane < 16) smax[wm * 256 + 64 * wn + 16 * nf + lane] = m;
    }
    __syncthreads();
    for (int h = tid; h < HID; h += 512) {
        float v = fmaxf(smax[h], smax[256 + h]) + conv_b[h];
        enc[n * HID + h] = fmaxf(v, 0.f);
    }
}

// ---------------- bag self-attention + relation scores ----------------
__global__ void bag_kernel(const float* __restrict__ enc, const int* __restrict__ X_Rel,
                           const float* __restrict__ rel_W, const float* __restrict__ rel_b,
                           float* __restrict__ out) {
    __shared__ float bagv[BB][232];
    __shared__ float bag2[BB][232];
    __shared__ float att[BB][BB];
    __shared__ float relv[232];
    __shared__ float repv[232];
    __shared__ float sc[BB], sc2[BB];
    const int b = blockIdx.x, t = threadIdx.x;

    for (int i = t; i < BB * HID; i += 256) {
        int r = i / HID, d = i % HID;
        bagv[r][d] = enc[(b * BB + r) * HID + d];
    }
    __syncthreads();
    if (t < 64) {
        int i = t >> 3, j = t & 7;
        float acc = 0.f;
        for (int d = 0; d < HID; ++d) acc += bagv[i][d] * bagv[j][d];
        att[i][j] = acc * (1.0f / sqrtf(230.0f));
    }
    __syncthreads();
    if (t < 8) {
        float m = att[t][0];
        for (int j = 1; j < 8; ++j) m = fmaxf(m, att[t][j]);
        float e[8], s = 0.f;
        for (int j = 0; j < 8; ++j) { e[j] = expf(att[t][j] - m); s += e[j]; }
        float inv = 1.f / s;
        for (int j = 0; j < 8; ++j) att[t][j] = e[j] * inv;
    }
    __syncthreads();
    for (int i = t; i < BB * HID; i += 256) {
        int r = i / HID, d = i % HID;
        float acc = 0.f;
        for (int j = 0; j < 8; ++j) acc += att[r][j] * bagv[j][d];
        bag2[r][d] = acc;
    }
    if (t < HID) relv[t] = rel_W[X_Rel[b] * HID + t];
    __syncthreads();
    if (t < 8) {
        float acc = 0.f;
        for (int d = 0; d < HID; ++d) acc += bag2[t][d] * relv[d];
        sc[t] = acc;
    }
    __syncthreads();
    if (t < 8) {
        float m = sc[0];
        for (int j = 1; j < 8; ++j) m = fmaxf(m, sc[j]);
        sc2[t] = expf(sc[t] - m);
    }
    __syncthreads();
    if (t < HID) {
        float sum = 0.f;
        for (int j = 0; j < 8; ++j) sum += sc2[j];
        float acc = 0.f;
        for (int j = 0; j < 8; ++j) acc += sc2[j] * bag2[j][t];
        repv[t] = acc / sum;
    }
    __syncthreads();
    if (t < RELN) {
        float acc = rel_b[t];
        for (int d = 0; d < HID; ++d) acc += repv[d] * rel_W[t * HID + d];
        out[b * RELN + t] = acc;
    }
}

extern "C" void kernel_launch(void* const* d_in, const int* in_sizes, int n_in,
                              void* d_out, int out_size, void* d_ws, size_t ws_size,
                              hipStream_t stream) {
    const int* X       = (const int*)d_in[0];
    const int* XP1     = (const int*)d_in[1];
    const int* XP2     = (const int*)d_in[2];
    const int* E1      = (const int*)d_in[3];
    const int* E2      = (const int*)d_in[4];
    const int* Q       = (const int*)d_in[10];
    const int* X_Rel   = (const int*)d_in[11];
    const float* W_word = (const float*)d_in[12];
    const float* W_pos1 = (const float*)d_in[13];
    const float* W_pos2 = (const float*)d_in[14];
    const float* w_s   = (const float*)d_in[15];
    const float* b_s   = (const float*)d_in[16];
    const float* w_q   = (const float*)d_in[17];
    const float* b_q   = (const float*)d_in[18];
    const float* w_sq  = (const float*)d_in[19];
    const float* b_sq  = (const float*)d_in[20];
    const float* conv_W = (const float*)d_in[21];
    const float* conv_b = (const float*)d_in[22];
    const float* rel_W = (const float*)d_in[23];
    const float* rel_b = (const float*)d_in[24];
    float* out = (float*)d_out;

    char* ws = (char*)d_ws;
    float* q_ws = (float*)ws;                      // 512*8*50 f32
    float* enc  = q_ws + BAGS * QL * WD;           // 4096*230 f32
    short* wt   = (short*)(enc + NSENT * HID);     // 256*480 bf16

    build_q_kernel<<<BAGS, 64, 0, stream>>>(Q, E1, E2, W_word, q_ws);
    pack_w_kernel<<<(256 * KTOT) / 256, 256, 0, stream>>>(conv_W, wt);

    const size_t lds_bytes =
        (size_t)XROWS * XROW * 2                     // xl          43680
        + 128 * 32 * 2 + 64 * 32 * 2 + 16 * 64 * 2  // abf/qtb/qwb 14336
        + 4 * (LLEN * 8 + LLEN + LLEN + QL + 52 + 512 + 2)  // f32 scratch
        + 4 * (3 * LLEN);                            // int idx
    sent_kernel<<<NSENT, 512, lds_bytes, stream>>>(
        X, XP1, XP2, W_word, W_pos1, W_pos2,
        w_s, b_s, w_q, b_q, w_sq, b_sq, conv_b, q_ws, wt, enc);

    bag_kernel<<<BAGS, 256, 0, stream>>>(enc, X_Rel, rel_W, rel_b, out);
}